// Round 8
// baseline (805.663 us; speedup 1.0000x reference)
//
#include <hip/hip_runtime.h>
#include <math.h>

typedef short s16x8 __attribute__((ext_vector_type(8)));
typedef float f32x4 __attribute__((ext_vector_type(4)));

#define SLOPE 0.2f
#define K1 1433
#define KP 1440   // K padded to multiple of 32
#define NKB 45    // KP/32

static __device__ __forceinline__ float leaky(float x) {
  return x > 0.f ? x : SLOPE * x;
}

static __device__ __forceinline__ unsigned short f2bf(float f) {
  unsigned u = __builtin_bit_cast(unsigned, f);
  u += 0x7FFFu + ((u >> 16) & 1u);
  return (unsigned short)(u >> 16);
}
static __device__ __forceinline__ float bf2f(unsigned short h) {
  unsigned u = ((unsigned)h) << 16;
  return __builtin_bit_cast(float, u);
}

// --------- W1 -> fragment-order bf16(hi) table ---------
// chunk index = kb*16 + ntg; value = W1[k][n], n = ntg*16 + (l&15),
// k = kb*32 + (l>>4)*8 + e (0 pad k>=K1)
__global__ void w1t_kernel(const float* __restrict__ W1,
                           unsigned short* __restrict__ w1f) {
  int tid = blockIdx.x * 256 + threadIdx.x;       // one thread = one 16B chunk
  if (tid >= NKB * 16 * 64) return;
  int l = tid & 63;
  int chunk = tid >> 6;                            // kb*16 + ntg
  int ntg = chunk & 15;
  int kb = chunk >> 4;
  int n = ntg * 16 + (l & 15);
  int kbase = kb * 32 + (l >> 4) * 8;
  unsigned short o[8];
#pragma unroll
  for (int e = 0; e < 8; ++e) {
    int k = kbase + e;
    float v = (k < K1) ? W1[(long)k * 256 + n] : 0.f;
    o[e] = f2bf(v);
  }
  *(ulonglong2*)(w1f + (long)tid * 8) = *(ulonglong2*)o;
}

// --------- GEMM1: 2-term split A(hi,lo) x B(hi), A direct-to-register ---------
// block: 256 thr = 4 waves (2m x 2n), wave tile 32x128. BM=64, BN=256, BK=32.
// A: each lane loads its own MFMA fragment data (2 rows x 32B) from global --
// no LDS for A, no staging barrier coupling. B: gll double-buffer, 2x16KB LDS.
__global__ __launch_bounds__(256, 3) void gemm1_mfma_kernel(
    const float* __restrict__ A, const unsigned short* __restrict__ w1f,
    float* __restrict__ C, int M) {
  __shared__ unsigned short Bs[2][16 * 64 * 8];   // 2 x 16 KB
  const int t = threadIdx.x;
  const int w = t >> 6, l = t & 63;
  const int wm = w >> 1, wn = w & 1;
  const int row0 = blockIdx.x * 64;
  const int lrow = l & 15, lkg = l >> 4;

  f32x4 acc[2][8];
#pragma unroll
  for (int mt = 0; mt < 2; ++mt)
#pragma unroll
    for (int nt = 0; nt < 8; ++nt)
#pragma unroll
      for (int r = 0; r < 4; ++r) acc[mt][nt][r] = 0.f;

  const int r0 = row0 + wm * 32 + lrow;
  const int r1 = r0 + 16;
  const bool ok0 = r0 < M, ok1 = r1 < M;
  const float* a0 = A + (long)(ok0 ? r0 : 0) * K1 + lkg * 8;
  const float* a1 = A + (long)(ok1 ? r1 : 0) * K1 + lkg * 8;
  const float4 f4z = make_float4(0.f, 0.f, 0.f, 0.f);

  // stage B tile kb into Bs[buf] (4 x gll per wave, lane-linear dest)
  auto stage = [&](int kb, int buf) {
#pragma unroll
    for (int q = 0; q < 4; ++q) {
      int ng = w * 4 + q;
      const unsigned short* gsrc = w1f + (((long)kb * 16 + ng) * 64 + l) * 8;
      unsigned short* ldst = &Bs[buf][ng * 512];
      __builtin_amdgcn_global_load_lds(
          (const __attribute__((address_space(1))) unsigned int*)gsrc,
          (__attribute__((address_space(3))) unsigned int*)ldst, 16, 0, 0);
    }
  };

  // load this lane's A fragment data for K-step kb (2 rows x 8 floats)
  auto loada = [&](int kb, float4* v) {
    if (kb < NKB - 1) {
      v[0] = ok0 ? *(const float4*)(a0 + kb * 32) : f4z;
      v[1] = ok0 ? *(const float4*)(a0 + kb * 32 + 4) : f4z;
      v[2] = ok1 ? *(const float4*)(a1 + kb * 32) : f4z;
      v[3] = ok1 ? *(const float4*)(a1 + kb * 32 + 4) : f4z;
    } else {          // kb == 44: k = 1408 + lkg*8 + e, valid only k < 1433
      if (lkg < 3) {
        v[0] = ok0 ? *(const float4*)(a0 + kb * 32) : f4z;
        v[1] = ok0 ? *(const float4*)(a0 + kb * 32 + 4) : f4z;
        v[2] = ok1 ? *(const float4*)(a1 + kb * 32) : f4z;
        v[3] = ok1 ? *(const float4*)(a1 + kb * 32 + 4) : f4z;
      } else {        // only k=1432 valid
        v[0] = f4z; v[1] = f4z; v[2] = f4z; v[3] = f4z;
        v[0].x = ok0 ? a0[kb * 32] : 0.f;
        v[2].x = ok1 ? a1[kb * 32] : 0.f;
      }
    }
  };

  auto cvt2 = [&](const float4& x, const float4& y, s16x8& ah, s16x8& al) {
    float f[8] = {x.x, x.y, x.z, x.w, y.x, y.y, y.z, y.w};
#pragma unroll
    for (int e = 0; e < 8; ++e) {
      unsigned short h = f2bf(f[e]);
      ah[e] = (short)h;
      al[e] = (short)f2bf(f[e] - bf2f(h));
    }
  };

  auto compute = [&](int cur, const float4* v) {
    s16x8 ah0, al0, ah1, al1;
    cvt2(v[0], v[1], ah0, al0);
    cvt2(v[2], v[3], ah1, al1);
    const unsigned short* bp = &Bs[cur][wn * 8 * 512 + l * 8];
#pragma unroll
    for (int nt = 0; nt < 8; ++nt) {
      s16x8 bh = *(const s16x8*)(bp + nt * 512);
      acc[0][nt] = __builtin_amdgcn_mfma_f32_16x16x32_bf16(ah0, bh, acc[0][nt], 0, 0, 0);
      acc[0][nt] = __builtin_amdgcn_mfma_f32_16x16x32_bf16(al0, bh, acc[0][nt], 0, 0, 0);
      acc[1][nt] = __builtin_amdgcn_mfma_f32_16x16x32_bf16(ah1, bh, acc[1][nt], 0, 0, 0);
      acc[1][nt] = __builtin_amdgcn_mfma_f32_16x16x32_bf16(al1, bh, acc[1][nt], 0, 0, 0);
    }
  };

  float4 vA[4], vB[4];
  stage(0, 0);
  loada(0, vA);
  __syncthreads();

  for (int kb = 0; kb < NKB - 1; kb += 2) {
    stage(kb + 1, 1);
    loada(kb + 1, vB);
    compute(0, vA);
    __syncthreads();
    if (kb + 2 < NKB) {
      stage(kb + 2, 0);
      loada(kb + 2, vA);
    }
    compute(1, vB);
    __syncthreads();
  }
  compute(0, vA);   // step 44 (buf 0, staged + loaded in last iteration)

  // epilogue: D layout col = l&15, row = (l>>4)*4 + r (within 16x16 tile)
  const int crow4 = (l >> 4) * 4;
#pragma unroll
  for (int mt = 0; mt < 2; ++mt) {
#pragma unroll
    for (int r = 0; r < 4; ++r) {
      int grow = row0 + wm * 32 + mt * 16 + crow4 + r;
      if (grow < M) {
#pragma unroll
        for (int nt = 0; nt < 8; ++nt) {
          int gcol = wn * 128 + nt * 16 + lrow;
          C[(long)grow * 256 + gcol] = acc[mt][nt][r];
        }
      }
    }
  }
}

// ------- attention logits, layer 1 + emit bf16 copy of h1 -------
__global__ void alpha1_kernel(const float* __restrict__ h1,
    const float* __restrict__ a_src, const float* __restrict__ a_dst,
    float* __restrict__ as_o, float* __restrict__ ad_o,
    unsigned short* __restrict__ h1b, int N) {
  int i = blockIdx.x * blockDim.x + threadIdx.x;  // i = n*8+h
  if (i >= N * 8) return;
  int h = i & 7;
  const float* hp = h1 + (long)(i >> 3) * 256 + h * 32;
  const float* sp = a_src + h * 32;
  const float* dp = a_dst + h * 32;
  unsigned short ob[32];
  float s1 = 0.f, s2 = 0.f;
#pragma unroll
  for (int c = 0; c < 32; c += 4) {
    float4 v = *(const float4*)(hp + c);
    float4 ws = *(const float4*)(sp + c);
    float4 wd = *(const float4*)(dp + c);
    s1 += v.x * ws.x + v.y * ws.y + v.z * ws.z + v.w * ws.w;
    s2 += v.x * wd.x + v.y * wd.y + v.z * wd.z + v.w * wd.w;
    ob[c] = f2bf(v.x); ob[c + 1] = f2bf(v.y);
    ob[c + 2] = f2bf(v.z); ob[c + 3] = f2bf(v.w);
  }
  as_o[i] = s1;
  ad_o[i] = s2;
  unsigned short* op = h1b + (long)(i >> 3) * 256 + h * 32;
#pragma unroll
  for (int c = 0; c < 32; c += 8)
    *(ulonglong2*)(op + c) = *(ulonglong2*)(ob + c);
}

// ================= CSR construction =================
__global__ void hist_kernel(const int* __restrict__ dst, int* __restrict__ cnt,
                            int E, int N) {
  int e = blockIdx.x * blockDim.x + threadIdx.x;
  if (e >= E + N) return;
  int d = (e < E) ? dst[e] : (e - E);
  atomicAdd(&cnt[d], 1);
}

__global__ __launch_bounds__(1024) void scan_kernel(
    const int* __restrict__ cnt, int* __restrict__ rowptr,
    int* __restrict__ cursor, int N) {
  __shared__ int part[1024];
  const int tid = threadIdx.x;
  const int chunk = (N + 1023) / 1024;
  const int base = tid * chunk;
  const int lim = min(base + chunk, N);
  int sum = 0;
  for (int i = base; i < lim; ++i) sum += cnt[i];
  part[tid] = sum;
  __syncthreads();
  for (int off = 1; off < 1024; off <<= 1) {
    int v = (tid >= off) ? part[tid - off] : 0;
    __syncthreads();
    part[tid] += v;
    __syncthreads();
  }
  int run = (tid == 0) ? 0 : part[tid - 1];
  for (int i = base; i < lim; ++i) {
    rowptr[i] = run;
    cursor[i] = run;
    run += cnt[i];
  }
  if (tid == 1023) rowptr[N] = part[1023];
}

__global__ void scatter_kernel(const int* __restrict__ src,
    const int* __restrict__ dst, int* __restrict__ cursor,
    int* __restrict__ csr_src, int E, int N) {
  int e = blockIdx.x * blockDim.x + threadIdx.x;
  if (e >= E + N) return;
  int s, d;
  if (e < E) { s = src[e]; d = dst[e]; } else { s = e - E; d = s; }
  int pos = atomicAdd(&cursor[d], 1);
  csr_src[pos] = s;
}

// ======== layer-1 fused aggregation: wave per dst, depth-2 pipeline ========
__global__ __launch_bounds__(256) void agg1_fused_kernel(
    const int* __restrict__ rowptr, const int* __restrict__ csr_src,
    const float* __restrict__ as_, const float* __restrict__ ad_,
    const unsigned short* __restrict__ h1b, const float* __restrict__ bias,
    float* __restrict__ act, int N) {
  int d = blockIdx.x * 4 + (threadIdx.x >> 6);
  if (d >= N) return;
  int l = threadIdx.x & 63;
  int h = l >> 3;
  int rs = rowptr[d], re = rowptr[d + 1];
  float adv = ad_[d * 8 + h];
  float4 acc = make_float4(0.f, 0.f, 0.f, 0.f);
  float den = 0.f;
  // pipeline: index + logit-operand fetched one iteration ahead
  int sN = csr_src[rs];
  float asN = as_[sN * 8 + h];
  for (int i = rs; i < re; ++i) {
    int sC = sN;
    float asC = asN;
    if (i + 1 < re) {
      sN = csr_src[i + 1];
      asN = as_[sN * 8 + h];
    }
    float a = __expf(leaky(asC + adv));
    ushort4 u = *(const ushort4*)(h1b + (long)sC * 256 + l * 4);
    den += a;
    acc.x += a * bf2f(u.x); acc.y += a * bf2f(u.y);
    acc.z += a * bf2f(u.z); acc.w += a * bf2f(u.w);
  }
  float inv = 1.f / den;
  float4 b = *(const float4*)(bias + l * 4);
  float4 o;
  o.x = acc.x * inv + b.x; o.y = acc.y * inv + b.y;
  o.z = acc.z * inv + b.z; o.w = acc.w * inv + b.w;
  o.x = o.x > 0.f ? o.x : expm1f(o.x);
  o.y = o.y > 0.f ? o.y : expm1f(o.y);
  o.z = o.z > 0.f ? o.z : expm1f(o.z);
  o.w = o.w > 0.f ? o.w : expm1f(o.w);
  *(float4*)(act + (long)d * 256 + l * 4) = o;
}

// ---------------- GEMM2 (K=256, N=56) + fused alpha2, bf16 h2 ----------------
__global__ __launch_bounds__(256) void gemm2_kernel(const float* __restrict__ act,
    const float* __restrict__ W2, const float* __restrict__ a_src2,
    const float* __restrict__ a_dst2, unsigned short* __restrict__ h2b,
    float* __restrict__ as_o, float* __restrict__ ad_o, int N) {
  __shared__ float Ws[256 * 56];
  for (int i = threadIdx.x; i < 256 * 56; i += 256) Ws[i] = W2[i];
  __syncthreads();
  int n = blockIdx.x * 32 + (threadIdx.x >> 3);
  int h = threadIdx.x & 7;
  if (n >= N) return;
  const float* ap = act + (long)n * 256;
  float acc[7] = {0.f, 0.f, 0.f, 0.f, 0.f, 0.f, 0.f};
  for (int k0 = 0; k0 < 256; k0 += 4) {
    float4 a = *(const float4*)(ap + k0);
    float av[4] = {a.x, a.y, a.z, a.w};
#pragma unroll
    for (int kk = 0; kk < 4; ++kk) {
      const float* wp = &Ws[(k0 + kk) * 56 + h * 7];
#pragma unroll
      for (int j = 0; j < 7; ++j) acc[j] += av[kk] * wp[j];
    }
  }
  unsigned short* hp = h2b + (long)n * 56 + h * 7;
  float s1 = 0.f, s2 = 0.f;
#pragma unroll
  for (int j = 0; j < 7; ++j) {
    hp[j] = f2bf(acc[j]);
    s1 += acc[j] * a_src2[h * 7 + j];
    s2 += acc[j] * a_dst2[h * 7 + j];
  }
  as_o[n * 8 + h] = s1;
  ad_o[n * 8 + h] = s2;
}

// ======== layer-2 fused aggregation: wave per dst, depth-2 pipeline ========
__global__ __launch_bounds__(256) void agg2_fused_kernel(
    const int* __restrict__ rowptr, const int* __restrict__ csr_src,
    const float* __restrict__ as_, const float* __restrict__ ad_,
    const unsigned short* __restrict__ h2b, const float* __restrict__ bias,
    float* __restrict__ out, int N) {
  int d = blockIdx.x * 4 + (threadIdx.x >> 6);
  if (d >= N) return;
  int l = threadIdx.x & 63;
  int h = l >> 3, j = l & 7;
  int rs = rowptr[d], re = rowptr[d + 1];
  float adv = ad_[d * 8 + h];
  float acc = 0.f, den = 0.f;
  int sN = csr_src[rs];
  float asN = as_[sN * 8 + h];
  for (int i = rs; i < re; ++i) {
    int sC = sN;
    float asC = asN;
    if (i + 1 < re) {
      sN = csr_src[i + 1];
      asN = as_[sN * 8 + h];
    }
    float a = __expf(leaky(asC + adv));
    den += a;
    if (j < 7) acc += a * bf2f(h2b[(long)sC * 56 + h * 7 + j]);
  }
  if (j < 7) out[(long)d * 56 + h * 7 + j] = acc / den + bias[h * 7 + j];
}

extern "C" void kernel_launch(void* const* d_in, const int* in_sizes, int n_in,
                              void* d_out, int out_size, void* d_ws, size_t ws_size,
                              hipStream_t stream) {
  const float* x    = (const float*)d_in[0];
  const int*   ei   = (const int*)d_in[1];
  const float* W1   = (const float*)d_in[2];
  const float* asr1 = (const float*)d_in[3];
  const float* adt1 = (const float*)d_in[4];
  const float* b1   = (const float*)d_in[5];
  const float* W2   = (const float*)d_in[6];
  const float* asr2 = (const float*)d_in[7];
  const float* adt2 = (const float*)d_in[8];
  const float* b2   = (const float*)d_in[9];
  float* out = (float*)d_out;

  const int N = in_sizes[0] / K1;
  const int E = in_sizes[1] / 2;
  const int* src = ei;
  const int* dst = ei + E;

  float* ws = (float*)d_ws;
  float* h1  = ws; ws += (long)N * 256;
  float* act = ws; ws += (long)N * 256;
  float* as1 = ws; ws += N * 8;
  float* ad1 = ws; ws += N * 8;
  float* as2 = ws; ws += N * 8;
  float* ad2 = ws; ws += N * 8;
  unsigned short* h1b = (unsigned short*)ws; ws += (long)N * 128;  // N*256 bf16
  unsigned short* h2b = (unsigned short*)ws; ws += (long)N * 28;   // N*56 bf16
  unsigned short* w1f = (unsigned short*)ws; ws += NKB * 16 * 64 * 8 / 2;
  int* cnt     = (int*)ws; ws += N;
  int* rowptr  = (int*)ws; ws += N + 1;
  int* cursor  = (int*)ws; ws += N;
  int* csr_src = (int*)ws; ws += E + N;

  hipMemsetAsync(cnt, 0, (size_t)N * sizeof(int), stream);

  dim3 blk(256);

  // CSR build + weight re-layout (cheap)
  hist_kernel<<<dim3((E + N + 255) / 256), blk, 0, stream>>>(dst, cnt, E, N);
  scan_kernel<<<dim3(1), dim3(1024), 0, stream>>>(cnt, rowptr, cursor, N);
  scatter_kernel<<<dim3((E + N + 255) / 256), blk, 0, stream>>>(
      src, dst, cursor, csr_src, E, N);
  {
    int tot = NKB * 16 * 64;
    w1t_kernel<<<dim3((tot + 255) / 256), blk, 0, stream>>>(W1, w1f);
  }

  gemm1_mfma_kernel<<<dim3((N + 63) / 64), blk, 0, stream>>>(x, w1f, h1, N);
  alpha1_kernel<<<dim3((N * 8 + 255) / 256), blk, 0, stream>>>(
      h1, asr1, adt1, as1, ad1, h1b, N);
  agg1_fused_kernel<<<dim3((N + 3) / 4), blk, 0, stream>>>(
      rowptr, csr_src, as1, ad1, h1b, b1, act, N);
  gemm2_kernel<<<dim3((N + 31) / 32), blk, 0, stream>>>(
      act, W2, asr2, adt2, h2b, as2, ad2, N);
  agg2_fused_kernel<<<dim3((N + 3) / 4), blk, 0, stream>>>(
      rowptr, csr_src, as2, ad2, h2b, b2, out, N);
}

// Round 11
// 781.505 us; speedup vs baseline: 1.0309x; 1.0309x over previous
//
#include <hip/hip_runtime.h>
#include <math.h>

typedef short s16x8 __attribute__((ext_vector_type(8)));
typedef float f32x4 __attribute__((ext_vector_type(4)));

#define SLOPE 0.2f
#define K1 1433
#define KP 1440   // K padded to multiple of 32
#define NKB 45    // KP/32

static __device__ __forceinline__ float leaky(float x) {
  return x > 0.f ? x : SLOPE * x;
}

static __device__ __forceinline__ unsigned short f2bf(float f) {
  unsigned u = __builtin_bit_cast(unsigned, f);
  u += 0x7FFFu + ((u >> 16) & 1u);
  return (unsigned short)(u >> 16);
}
static __device__ __forceinline__ float bf2f(unsigned short h) {
  unsigned u = ((unsigned)h) << 16;
  return __builtin_bit_cast(float, u);
}

// --------- W1 -> fragment-order bf16(hi) table ---------
// chunk index = kb*16 + ng; value = W1[k][n], n = ng*16 + (l&15),
// k = kb*32 + (l>>4)*8 + e (0 pad k>=K1)
__global__ void w1t_kernel(const float* __restrict__ W1,
                           unsigned short* __restrict__ w1f) {
  int tid = blockIdx.x * 256 + threadIdx.x;       // one thread = one 16B chunk
  if (tid >= NKB * 16 * 64) return;
  int l = tid & 63;
  int chunk = tid >> 6;                            // kb*16 + ng
  int ng = chunk & 15;
  int kb = chunk >> 4;
  int n = ng * 16 + (l & 15);
  int kbase = kb * 32 + (l >> 4) * 8;
  unsigned short o[8];
#pragma unroll
  for (int e = 0; e < 8; ++e) {
    int k = kbase + e;
    float v = (k < K1) ? W1[(long)k * 256 + n] : 0.f;
    o[e] = f2bf(v);
  }
  *(ulonglong2*)(w1f + (long)tid * 8) = *(ulonglong2*)o;
}

// --------- GEMM1: 2-term split A(hi,lo) x B(hi), all-register, NO barriers ---
// block: 256 thr = 4 waves (2m x 2n), wave tile 32x128. BM=64, BN=256, BK=32.
// A: per-lane fragment loads from global (prefetch distance 2).
// B: per-lane fragment loads from w1f (L2-resident, prefetch distance 1).
// No LDS, no __syncthreads -> waves fully decoupled.
__global__ __launch_bounds__(256, 2) void gemm1_mfma_kernel(
    const float* __restrict__ A, const unsigned short* __restrict__ w1f,
    unsigned short* __restrict__ h1b, int M) {
  const int t = threadIdx.x;
  const int w = t >> 6, l = t & 63;
  const int wm = w >> 1, wn = w & 1;
  const int row0 = blockIdx.x * 64;
  const int lrow = l & 15, lkg = l >> 4;

  f32x4 acc[2][8];
#pragma unroll
  for (int mt = 0; mt < 2; ++mt)
#pragma unroll
    for (int nt = 0; nt < 8; ++nt)
#pragma unroll
      for (int r = 0; r < 4; ++r) acc[mt][nt][r] = 0.f;

  const int r0 = row0 + wm * 32 + lrow;
  const int r1 = r0 + 16;
  const bool ok0 = r0 < M, ok1 = r1 < M;
  const float* a0 = A + (long)(ok0 ? r0 : 0) * K1 + lkg * 8;
  const float* a1 = A + (long)(ok1 ? r1 : 0) * K1 + lkg * 8;
  const float4 f4z = make_float4(0.f, 0.f, 0.f, 0.f);

  // load this lane's A fragment data for K-step kb (2 rows x 8 floats)
  auto la = [&](int kb, float4* v) {
    if (kb < NKB - 1) {
      v[0] = ok0 ? *(const float4*)(a0 + kb * 32) : f4z;
      v[1] = ok0 ? *(const float4*)(a0 + kb * 32 + 4) : f4z;
      v[2] = ok1 ? *(const float4*)(a1 + kb * 32) : f4z;
      v[3] = ok1 ? *(const float4*)(a1 + kb * 32 + 4) : f4z;
    } else {          // kb == 44: k = 1408 + lkg*8 + e, valid only k < 1433
      if (lkg < 3) {
        v[0] = ok0 ? *(const float4*)(a0 + kb * 32) : f4z;
        v[1] = ok0 ? *(const float4*)(a0 + kb * 32 + 4) : f4z;
        v[2] = ok1 ? *(const float4*)(a1 + kb * 32) : f4z;
        v[3] = ok1 ? *(const float4*)(a1 + kb * 32 + 4) : f4z;
      } else {        // only k=1432 valid
        v[0] = f4z; v[1] = f4z; v[2] = f4z; v[3] = f4z;
        v[0].x = ok0 ? a0[kb * 32] : 0.f;
        v[2].x = ok1 ? a1[kb * 32] : 0.f;
      }
    }
  };

  // load this lane's 8 B fragments for K-step kb (lane-linear, L2-resident)
  auto lb = [&](int kb, s16x8* b) {
    const unsigned short* bp = w1f + (((long)kb * 16 + wn * 8) * 64 + l) * 8;
#pragma unroll
    for (int nt = 0; nt < 8; ++nt)
      b[nt] = *(const s16x8*)(bp + nt * 512);
  };

  auto cvt2 = [&](const float4& x, const float4& y, s16x8& ah, s16x8& al) {
    float f[8] = {x.x, x.y, x.z, x.w, y.x, y.y, y.z, y.w};
#pragma unroll
    for (int e = 0; e < 8; ++e) {
      unsigned short h = f2bf(f[e]);
      ah[e] = (short)h;
      al[e] = (short)f2bf(f[e] - bf2f(h));
    }
  };

  auto compute = [&](const float4* v, const s16x8* b) {
    s16x8 ah0, al0, ah1, al1;
    cvt2(v[0], v[1], ah0, al0);
    cvt2(v[2], v[3], ah1, al1);
#pragma unroll
    for (int nt = 0; nt < 8; ++nt) {
      acc[0][nt] = __builtin_amdgcn_mfma_f32_16x16x32_bf16(ah0, b[nt], acc[0][nt], 0, 0, 0);
      acc[0][nt] = __builtin_amdgcn_mfma_f32_16x16x32_bf16(al0, b[nt], acc[0][nt], 0, 0, 0);
      acc[1][nt] = __builtin_amdgcn_mfma_f32_16x16x32_bf16(ah1, b[nt], acc[1][nt], 0, 0, 0);
      acc[1][nt] = __builtin_amdgcn_mfma_f32_16x16x32_bf16(al1, b[nt], acc[1][nt], 0, 0, 0);
    }
  };

  float4 A0[4], A1[4];
  s16x8 B0[8], B1[8];
  la(0, A0);
  la(1, A1);
  lb(0, B0);

#pragma unroll 1
  for (int kb = 0; kb < NKB - 1; kb += 2) {
    lb(kb + 1, B1);
    compute(A0, B0);
    la(kb + 2, A0);                 // distance-2 prefetch into freed slot
    lb(kb + 2 < NKB ? kb + 2 : NKB - 1, B0);
    compute(A1, B1);
    la(kb + 3 < NKB ? kb + 3 : NKB - 1, A1);  // clamped (unused if OOB)
  }
  compute(A0, B0);                  // step 44

  // epilogue: D layout col = l&15, row = (l>>4)*4 + r; write bf16 h1b
  const int crow4 = (l >> 4) * 4;
#pragma unroll
  for (int mt = 0; mt < 2; ++mt) {
#pragma unroll
    for (int r = 0; r < 4; ++r) {
      int grow = row0 + wm * 32 + mt * 16 + crow4 + r;
      if (grow < M) {
#pragma unroll
        for (int nt = 0; nt < 8; ++nt) {
          int gcol = wn * 128 + nt * 16 + lrow;
          h1b[(long)grow * 256 + gcol] = f2bf(acc[mt][nt][r]);
        }
      }
    }
  }
}

// ------- attention logits, layer 1 (reads bf16 h1b) -------
__global__ void alpha1_kernel(const unsigned short* __restrict__ h1b,
    const float* __restrict__ a_src, const float* __restrict__ a_dst,
    float* __restrict__ as_o, float* __restrict__ ad_o, int N) {
  int i = blockIdx.x * blockDim.x + threadIdx.x;  // i = n*8+h
  if (i >= N * 8) return;
  int h = i & 7;
  const unsigned short* hp = h1b + (long)(i >> 3) * 256 + h * 32;
  const float* sp = a_src + h * 32;
  const float* dp = a_dst + h * 32;
  float s1 = 0.f, s2 = 0.f;
#pragma unroll
  for (int c = 0; c < 32; c += 4) {
    ushort4 u = *(const ushort4*)(hp + c);
    float4 ws = *(const float4*)(sp + c);
    float4 wd = *(const float4*)(dp + c);
    float vx = bf2f(u.x), vy = bf2f(u.y), vz = bf2f(u.z), vw = bf2f(u.w);
    s1 += vx * ws.x + vy * ws.y + vz * ws.z + vw * ws.w;
    s2 += vx * wd.x + vy * wd.y + vz * wd.z + vw * wd.w;
  }
  as_o[i] = s1;
  ad_o[i] = s2;
}

// ================= CSR construction =================
__global__ void hist_kernel(const int* __restrict__ dst, int* __restrict__ cnt,
                            int E, int N) {
  int e = blockIdx.x * blockDim.x + threadIdx.x;
  if (e >= E + N) return;
  int d = (e < E) ? dst[e] : (e - E);
  atomicAdd(&cnt[d], 1);
}

__global__ __launch_bounds__(1024) void scan_kernel(
    const int* __restrict__ cnt, int* __restrict__ rowptr,
    int* __restrict__ cursor, int N) {
  __shared__ int part[1024];
  const int tid = threadIdx.x;
  const int chunk = (N + 1023) / 1024;
  const int base = tid * chunk;
  const int lim = min(base + chunk, N);
  int sum = 0;
  for (int i = base; i < lim; ++i) sum += cnt[i];
  part[tid] = sum;
  __syncthreads();
  for (int off = 1; off < 1024; off <<= 1) {
    int v = (tid >= off) ? part[tid - off] : 0;
    __syncthreads();
    part[tid] += v;
    __syncthreads();
  }
  int run = (tid == 0) ? 0 : part[tid - 1];
  for (int i = base; i < lim; ++i) {
    rowptr[i] = run;
    cursor[i] = run;
    run += cnt[i];
  }
  if (tid == 1023) rowptr[N] = part[1023];
}

__global__ void scatter_kernel(const int* __restrict__ src,
    const int* __restrict__ dst, int* __restrict__ cursor,
    int* __restrict__ csr_src, int E, int N) {
  int e = blockIdx.x * blockDim.x + threadIdx.x;
  if (e >= E + N) return;
  int s, d;
  if (e < E) { s = src[e]; d = dst[e]; } else { s = e - E; d = s; }
  int pos = atomicAdd(&cursor[d], 1);
  csr_src[pos] = s;
}

// ======== layer-1 fused aggregation: wave per dst, depth-2 pipeline ========
__global__ __launch_bounds__(256) void agg1_fused_kernel(
    const int* __restrict__ rowptr, const int* __restrict__ csr_src,
    const float* __restrict__ as_, const float* __restrict__ ad_,
    const unsigned short* __restrict__ h1b, const float* __restrict__ bias,
    float* __restrict__ act, int N) {
  int d = blockIdx.x * 4 + (threadIdx.x >> 6);
  if (d >= N) return;
  int l = threadIdx.x & 63;
  int h = l >> 3;
  int rs = rowptr[d], re = rowptr[d + 1];
  float adv = ad_[d * 8 + h];
  float4 acc = make_float4(0.f, 0.f, 0.f, 0.f);
  float den = 0.f;
  int sN = csr_src[rs];
  float asN = as_[sN * 8 + h];
  for (int i = rs; i < re; ++i) {
    int sC = sN;
    float asC = asN;
    if (i + 1 < re) {
      sN = csr_src[i + 1];
      asN = as_[sN * 8 + h];
    }
    float a = __expf(leaky(asC + adv));
    ushort4 u = *(const ushort4*)(h1b + (long)sC * 256 + l * 4);
    den += a;
    acc.x += a * bf2f(u.x); acc.y += a * bf2f(u.y);
    acc.z += a * bf2f(u.z); acc.w += a * bf2f(u.w);
  }
  float inv = 1.f / den;
  float4 b = *(const float4*)(bias + l * 4);
  float4 o;
  o.x = acc.x * inv + b.x; o.y = acc.y * inv + b.y;
  o.z = acc.z * inv + b.z; o.w = acc.w * inv + b.w;
  o.x = o.x > 0.f ? o.x : expm1f(o.x);
  o.y = o.y > 0.f ? o.y : expm1f(o.y);
  o.z = o.z > 0.f ? o.z : expm1f(o.z);
  o.w = o.w > 0.f ? o.w : expm1f(o.w);
  *(float4*)(act + (long)d * 256 + l * 4) = o;
}

// -------- GEMM2 (K=256, N=56) + fused alpha2, 8-padded bf16 h2 --------
__global__ __launch_bounds__(256) void gemm2_kernel(const float* __restrict__ act,
    const float* __restrict__ W2, const float* __restrict__ a_src2,
    const float* __restrict__ a_dst2, unsigned short* __restrict__ h2p,
    float* __restrict__ as_o, float* __restrict__ ad_o, int N) {
  __shared__ float Ws[256 * 56];
  for (int i = threadIdx.x; i < 256 * 56; i += 256) Ws[i] = W2[i];
  __syncthreads();
  int n = blockIdx.x * 32 + (threadIdx.x >> 3);
  int h = threadIdx.x & 7;
  if (n >= N) return;
  const float* ap = act + (long)n * 256;
  float acc[7] = {0.f, 0.f, 0.f, 0.f, 0.f, 0.f, 0.f};
  for (int k0 = 0; k0 < 256; k0 += 4) {
    float4 a = *(const float4*)(ap + k0);
    float av[4] = {a.x, a.y, a.z, a.w};
#pragma unroll
    for (int kk = 0; kk < 4; ++kk) {
      const float* wp = &Ws[(k0 + kk) * 56 + h * 7];
#pragma unroll
      for (int j = 0; j < 7; ++j) acc[j] += av[kk] * wp[j];
    }
  }
  unsigned short ob[8];
  float s1 = 0.f, s2 = 0.f;
#pragma unroll
  for (int j = 0; j < 7; ++j) {
    ob[j] = f2bf(acc[j]);
    s1 += acc[j] * a_src2[h * 7 + j];
    s2 += acc[j] * a_dst2[h * 7 + j];
  }
  ob[7] = 0;
  *(ulonglong2*)(h2p + (long)n * 64 + h * 8) = *(ulonglong2*)ob;
  as_o[n * 8 + h] = s1;
  ad_o[n * 8 + h] = s2;
}

// ======== layer-2 fused aggregation: wave per dst, coalesced 128B gather ====
__global__ __launch_bounds__(256) void agg2_fused_kernel(
    const int* __restrict__ rowptr, const int* __restrict__ csr_src,
    const float* __restrict__ as_, const float* __restrict__ ad_,
    const unsigned short* __restrict__ h2p, const float* __restrict__ bias,
    float* __restrict__ out, int N) {
  int d = blockIdx.x * 4 + (threadIdx.x >> 6);
  if (d >= N) return;
  int l = threadIdx.x & 63;
  int h = l >> 3, j = l & 7;
  int rs = rowptr[d], re = rowptr[d + 1];
  float adv = ad_[d * 8 + h];
  float acc = 0.f, den = 0.f;
  int sN = csr_src[rs];
  float asN = as_[sN * 8 + h];
  for (int i = rs; i < re; ++i) {
    int sC = sN;
    float asC = asN;
    if (i + 1 < re) {
      sN = csr_src[i + 1];
      asN = as_[sN * 8 + h];
    }
    float a = __expf(leaky(asC + adv));
    den += a;
    acc += a * bf2f(h2p[(long)sC * 64 + l]);   // pad lane reads 0
  }
  if (j < 7) out[(long)d * 56 + h * 7 + j] = acc / den + bias[h * 7 + j];
}

extern "C" void kernel_launch(void* const* d_in, const int* in_sizes, int n_in,
                              void* d_out, int out_size, void* d_ws, size_t ws_size,
                              hipStream_t stream) {
  const float* x    = (const float*)d_in[0];
  const int*   ei   = (const int*)d_in[1];
  const float* W1   = (const float*)d_in[2];
  const float* asr1 = (const float*)d_in[3];
  const float* adt1 = (const float*)d_in[4];
  const float* b1   = (const float*)d_in[5];
  const float* W2   = (const float*)d_in[6];
  const float* asr2 = (const float*)d_in[7];
  const float* adt2 = (const float*)d_in[8];
  const float* b2   = (const float*)d_in[9];
  float* out = (float*)d_out;

  const int N = in_sizes[0] / K1;
  const int E = in_sizes[1] / 2;
  const int* src = ei;
  const int* dst = ei + E;

  float* ws = (float*)d_ws;
  float* act = ws; ws += (long)N * 256;
  float* as1 = ws; ws += N * 8;
  float* ad1 = ws; ws += N * 8;
  float* as2 = ws; ws += N * 8;
  float* ad2 = ws; ws += N * 8;
  unsigned short* h1b = (unsigned short*)ws; ws += (long)N * 128;  // N*256 bf16
  unsigned short* h2p = (unsigned short*)ws; ws += (long)N * 32;   // N*64 bf16
  unsigned short* w1f = (unsigned short*)ws; ws += NKB * 16 * 64 * 8 / 2;
  int* cnt     = (int*)ws; ws += N;
  int* rowptr  = (int*)ws; ws += N + 1;
  int* cursor  = (int*)ws; ws += N;
  int* csr_src = (int*)ws; ws += E + N;

  hipMemsetAsync(cnt, 0, (size_t)N * sizeof(int), stream);

  dim3 blk(256);

  // CSR build + weight re-layout (cheap)
  hist_kernel<<<dim3((E + N + 255) / 256), blk, 0, stream>>>(dst, cnt, E, N);
  scan_kernel<<<dim3(1), dim3(1024), 0, stream>>>(cnt, rowptr, cursor, N);
  scatter_kernel<<<dim3((E + N + 255) / 256), blk, 0, stream>>>(
      src, dst, cursor, csr_src, E, N);
  {
    int tot = NKB * 16 * 64;
    w1t_kernel<<<dim3((tot + 255) / 256), blk, 0, stream>>>(W1, w1f);
  }

  gemm1_mfma_kernel<<<dim3((N + 63) / 64), blk, 0, stream>>>(x, w1f, h1b, N);
  alpha1_kernel<<<dim3((N * 8 + 255) / 256), blk, 0, stream>>>(
      h1b, asr1, adt1, as1, ad1, N);
  agg1_fused_kernel<<<dim3((N + 3) / 4), blk, 0, stream>>>(
      rowptr, csr_src, as1, ad1, h1b, b1, act, N);
  gemm2_kernel<<<dim3((N + 31) / 32), blk, 0, stream>>>(
      act, W2, asr2, adt2, h2p, as2, ad2, N);
  agg2_fused_kernel<<<dim3((N + 3) / 4), blk, 0, stream>>>(
      rowptr, csr_src, as2, ad2, h2p, b2, out, N);
}